// Round 1
// 563.218 us; speedup vs baseline: 1.0957x; 1.0957x over previous
//
#include <hip/hip_runtime.h>

#define NN 100000
#define DD 128
#define EE 1600000
#define BN_EPS 1e-5f

using bf16x8 = __attribute__((ext_vector_type(8))) short;
using f32x4  = __attribute__((ext_vector_type(4))) float;

__device__ __forceinline__ unsigned short bf16r(float f) {
    unsigned u = __float_as_uint(f);
    u += 0x7FFF + ((u >> 16) & 1);   // round-to-nearest-even
    return (unsigned short)(u >> 16);
}
__device__ __forceinline__ float bf2f(unsigned short h) {
    return __uint_as_float((unsigned)h << 16);
}

// ---------------- degree histogram (int4 edge loads) ----------------
__global__ void deg4_kernel(const int4* __restrict__ src4, const int4* __restrict__ dst4,
                            int* __restrict__ outdeg, int* __restrict__ indeg) {
    int i = blockIdx.x * blockDim.x + threadIdx.x;
    if (i < EE / 4) {
        int4 s = src4[i];
        int4 d = dst4[i];
        atomicAdd(&outdeg[s.x], 1); atomicAdd(&outdeg[s.y], 1);
        atomicAdd(&outdeg[s.z], 1); atomicAdd(&outdeg[s.w], 1);
        atomicAdd(&indeg[d.x], 1); atomicAdd(&indeg[d.y], 1);
        atomicAdd(&indeg[d.z], 1); atomicAdd(&indeg[d.w], 1);
    }
}

// ---------------- scan phase 1: per-block inclusive scan of indeg ----------------
__global__ __launch_bounds__(1024) void scan1_kernel(const int* __restrict__ indeg,
                                                     int* __restrict__ partial,
                                                     int* __restrict__ blocksum) {
    __shared__ int s[1024];
    int t = threadIdx.x;
    int idx = blockIdx.x * 1024 + t;
    int v = (idx < NN) ? indeg[idx] : 0;
    s[t] = v;
    __syncthreads();
    for (int off = 1; off < 1024; off <<= 1) {
        int x = (t >= off) ? s[t - off] : 0;
        __syncthreads();
        s[t] += x;
        __syncthreads();
    }
    if (idx < NN) partial[idx] = s[t] - v;  // exclusive within block
    if (t == 1023) blocksum[blockIdx.x] = s[t];
}

// ---------------- scan phases 2+3 fused: every block re-scans the 98 block sums ----------------
__global__ void scan23_kernel(const int* __restrict__ partial, const int* __restrict__ blocksum,
                              const int* __restrict__ outdeg, const int* __restrict__ indeg,
                              int* __restrict__ row_ofs, int* __restrict__ cursor,
                              float* __restrict__ ns, float* __restrict__ nd) {
    __shared__ int s[128];
    int t = threadIdx.x;
    if (t < 128) s[t] = (t < 98) ? blocksum[t] : 0;
    __syncthreads();
    for (int off = 1; off < 128; off <<= 1) {
        int x = (t < 128 && t >= off) ? s[t - off] : 0;
        __syncthreads();
        if (t < 128) s[t] += x;
        __syncthreads();
    }
    int i = blockIdx.x * blockDim.x + t;
    if (i < NN) {
        int bk = i >> 10;
        int ro = partial[i] + s[bk] - blocksum[bk];  // + exclusive block offset
        row_ofs[i] = ro;
        cursor[i] = ro;
        ns[i] = rsqrtf(fmaxf((float)outdeg[i], 1.0f));
        nd[i] = rsqrtf(fmaxf((float)indeg[i], 1.0f));
        if (i == 0) row_ofs[NN] = EE;
    }
}

// ---------------- feats -> bf16 pre-scaled by ns ----------------
__global__ void cvt_kernel(const float4* __restrict__ feats4, const float* __restrict__ ns,
                           ushort4* __restrict__ fb4) {
    int i = blockIdx.x * blockDim.x + threadIdx.x;  // NN*32 = 3.2M
    if (i < NN * 32) {
        float s = ns[i >> 5];
        float4 v = feats4[i];
        ushort4 h;
        h.x = bf16r(v.x * s);
        h.y = bf16r(v.y * s);
        h.z = bf16r(v.z * s);
        h.w = bf16r(v.w * s);
        fb4[i] = h;
    }
}

// ---------------- CSR fill (int4 edge loads) ----------------
__global__ void fill4_kernel(const int4* __restrict__ src4, const int4* __restrict__ dst4,
                             int* __restrict__ cursor, int* __restrict__ e_src) {
    int i = blockIdx.x * blockDim.x + threadIdx.x;
    if (i < EE / 4) {
        int4 s = src4[i];
        int4 d = dst4[i];
        e_src[atomicAdd(&cursor[d.x], 1)] = s.x;
        e_src[atomicAdd(&cursor[d.y], 1)] = s.y;
        e_src[atomicAdd(&cursor[d.z], 1)] = s.z;
        e_src[atomicAdd(&cursor[d.w], 1)] = s.w;
    }
}

// ---------------- weight pre-pack into MFMA B-fragment order, bf16 hi/lo ----------------
// layout: wb[(g*2+p)*32 + ct*4 + ks][lane 0..63][i 0..7] bf16, fragment = 1KB contiguous
// B-frag for mfma_f32_16x16x32_bf16: lane l, elem i -> B[k = ks*32 + (l>>4)*8 + i][col = ct*16 + (l&15)]
__global__ void prepw_kernel(const float* __restrict__ W, const float* __restrict__ Wr,
                             unsigned short* __restrict__ wb) {
    int g = blockIdx.x >> 5;          // 0 = W, 1 = Wr
    int f = blockIdx.x & 31;          // ct*4 + ks
    int ct = f >> 2, ks = f & 3;
    int l = threadIdx.x;              // 0..63
    const float* G = g ? Wr : W;
    unsigned short* hi = wb + (((size_t)(g * 2 + 0) * 32 + f) * 64 + l) * 8;
    unsigned short* lo = wb + (((size_t)(g * 2 + 1) * 32 + f) * 64 + l) * 8;
    for (int i = 0; i < 8; ++i) {
        int k = ks * 32 + (l >> 4) * 8 + i;
        int col = ct * 16 + (l & 15);
        float w = G[k * 128 + col];
        unsigned uh = __float_as_uint(w) & 0xFFFF0000u;  // truncated hi part
        hi[i] = (unsigned short)(uh >> 16);
        lo[i] = bf16r(w - __uint_as_float(uh));          // residual -> lo
    }
}

// ---------------- fused gather + dual MFMA GEMM + bias/relu/add + BN colsum ----------------
// block = 256 threads (4 waves), 32 nodes/block, 3125 blocks.
// LDS 33KB -> 4 blocks/CU; __launch_bounds__(256,4) caps VGPR at 128.
// A/F tiles stored bf16 hi/lo with XOR swizzle (byte ^= (row&7)<<4) so the
// stride-256B ds_read_b128 fragment reads are conflict-free (G4).
__global__ __launch_bounds__(256, 4) void gg_kernel(
    const float4* __restrict__ feats4, const ushort4* __restrict__ fb4,
    const float* __restrict__ nd,
    const int* __restrict__ row_ofs, const int* __restrict__ e_src,
    const unsigned short* __restrict__ wb,
    const float* __restrict__ b, const float* __restrict__ br,
    float* __restrict__ y, float* __restrict__ colsum, float* __restrict__ colsumsq) {
    __shared__ unsigned short AsH[32 * 128];
    __shared__ unsigned short AsL[32 * 128];
    __shared__ unsigned short FsH[32 * 128];
    __shared__ unsigned short FsL[32 * 128];
    __shared__ float redS[128];
    __shared__ float redQ[128];

    const int tid = threadIdx.x;
    const int block_row = blockIdx.x * 32;

    // ---- stage residual feats rows as bf16 hi/lo (swizzled) ----
    for (int i = tid; i < 1024; i += 256) {
        int r = i >> 5;
        int c4 = i & 31;
        float4 f = feats4[(size_t)(block_row + r) * 32 + c4];
        unsigned u0 = __float_as_uint(f.x) & 0xFFFF0000u;
        unsigned u1 = __float_as_uint(f.y) & 0xFFFF0000u;
        unsigned u2 = __float_as_uint(f.z) & 0xFFFF0000u;
        unsigned u3 = __float_as_uint(f.w) & 0xFFFF0000u;
        ushort4 h, lo;
        h.x = (unsigned short)(u0 >> 16);
        h.y = (unsigned short)(u1 >> 16);
        h.z = (unsigned short)(u2 >> 16);
        h.w = (unsigned short)(u3 >> 16);
        lo.x = bf16r(f.x - __uint_as_float(u0));
        lo.y = bf16r(f.y - __uint_as_float(u1));
        lo.z = bf16r(f.z - __uint_as_float(u2));
        lo.w = bf16r(f.w - __uint_as_float(u3));
        int off = (r * 256 + ((c4 * 8) ^ ((r & 7) << 4))) >> 1;  // ushort index, 8B aligned
        *(ushort4*)(&FsH[off]) = h;
        *(ushort4*)(&FsL[off]) = lo;
    }

    // ---- gather-aggregate from bf16 pre-scaled table: each 32-lane group does 4 nodes ----
    {
        const int lane = tid & 31;
        const int grp = tid >> 5;
        for (int n = 0; n < 4; ++n) {
            int nl = grp * 4 + n;
            int node = block_row + nl;
            int beg = row_ofs[node];
            int end = row_ofs[node + 1];
            float4 acc0 = {0.f, 0.f, 0.f, 0.f};
            float4 acc1 = {0.f, 0.f, 0.f, 0.f};
            int e = beg;
            for (; e + 3 < end; e += 4) {
                int s0 = e_src[e], s1 = e_src[e + 1], s2 = e_src[e + 2], s3 = e_src[e + 3];
                ushort4 u0 = fb4[s0 * 32 + lane];
                ushort4 u1 = fb4[s1 * 32 + lane];
                ushort4 u2 = fb4[s2 * 32 + lane];
                ushort4 u3 = fb4[s3 * 32 + lane];
                acc0.x += bf2f(u0.x); acc0.y += bf2f(u0.y); acc0.z += bf2f(u0.z); acc0.w += bf2f(u0.w);
                acc1.x += bf2f(u1.x); acc1.y += bf2f(u1.y); acc1.z += bf2f(u1.z); acc1.w += bf2f(u1.w);
                acc0.x += bf2f(u2.x); acc0.y += bf2f(u2.y); acc0.z += bf2f(u2.z); acc0.w += bf2f(u2.w);
                acc1.x += bf2f(u3.x); acc1.y += bf2f(u3.y); acc1.z += bf2f(u3.z); acc1.w += bf2f(u3.w);
            }
            for (; e < end; ++e) {
                int s0 = e_src[e];
                ushort4 u0 = fb4[s0 * 32 + lane];
                acc0.x += bf2f(u0.x); acc0.y += bf2f(u0.y); acc0.z += bf2f(u0.z); acc0.w += bf2f(u0.w);
            }
            float snd = nd[node];
            float ax = (acc0.x + acc1.x) * snd;
            float ay = (acc0.y + acc1.y) * snd;
            float az = (acc0.z + acc1.z) * snd;
            float aw = (acc0.w + acc1.w) * snd;
            unsigned u0 = __float_as_uint(ax) & 0xFFFF0000u;
            unsigned u1 = __float_as_uint(ay) & 0xFFFF0000u;
            unsigned u2 = __float_as_uint(az) & 0xFFFF0000u;
            unsigned u3 = __float_as_uint(aw) & 0xFFFF0000u;
            ushort4 h, lo;
            h.x = (unsigned short)(u0 >> 16);
            h.y = (unsigned short)(u1 >> 16);
            h.z = (unsigned short)(u2 >> 16);
            h.w = (unsigned short)(u3 >> 16);
            lo.x = bf16r(ax - __uint_as_float(u0));
            lo.y = bf16r(ay - __uint_as_float(u1));
            lo.z = bf16r(az - __uint_as_float(u2));
            lo.w = bf16r(aw - __uint_as_float(u3));
            int off = (nl * 256 + ((lane * 8) ^ ((nl & 7) << 4))) >> 1;
            *(ushort4*)(&AsH[off]) = h;
            *(ushort4*)(&AsL[off]) = lo;
        }
    }
    __syncthreads();

    // ---- MFMA phase: wave w covers all 32 rows x cols [w*32, w*32+31] ----
    const int w = tid >> 6;
    const int l = tid & 63;
    const int lr = l & 15;
    const int lh = l >> 4;
    const int ct0 = w * 2;
    const bf16x8* WB = (const bf16x8*)wb;

    const f32x4 fzero = {0.f, 0.f, 0.f, 0.f};
    f32x4 aC[2][2], aR[2][2];  // [row-frag][col-tile]
#pragma unroll
    for (int r = 0; r < 2; ++r)
#pragma unroll
        for (int c = 0; c < 2; ++c) { aC[r][c] = fzero; aR[r][c] = fzero; }

#pragma unroll 1
    for (int ks = 0; ks < 4; ++ks) {
        bf16x8 ah[2], al[2], fh[2], fl[2];
#pragma unroll
        for (int r = 0; r < 2; ++r) {
            int row = r * 16 + lr;
            int off = (row * 256 + ((ks * 64 + lh * 16) ^ ((row & 7) << 4))) >> 1;
            ah[r] = *(const bf16x8*)(&AsH[off]);
            al[r] = *(const bf16x8*)(&AsL[off]);
            fh[r] = *(const bf16x8*)(&FsH[off]);
            fl[r] = *(const bf16x8*)(&FsL[off]);
        }
#pragma unroll
        for (int c = 0; c < 2; ++c) {
            int fr = (ct0 + c) * 4 + ks;
            bf16x8 wh  = WB[(0 * 32 + fr) * 64 + l];
            bf16x8 wl  = WB[(1 * 32 + fr) * 64 + l];
            bf16x8 wrh = WB[(2 * 32 + fr) * 64 + l];
            bf16x8 wrl = WB[(3 * 32 + fr) * 64 + l];
#pragma unroll
            for (int r = 0; r < 2; ++r) {
                aC[r][c] = __builtin_amdgcn_mfma_f32_16x16x32_bf16(ah[r], wh, aC[r][c], 0, 0, 0);
                aC[r][c] = __builtin_amdgcn_mfma_f32_16x16x32_bf16(al[r], wh, aC[r][c], 0, 0, 0);
                aC[r][c] = __builtin_amdgcn_mfma_f32_16x16x32_bf16(ah[r], wl, aC[r][c], 0, 0, 0);
                aR[r][c] = __builtin_amdgcn_mfma_f32_16x16x32_bf16(fh[r], wrh, aR[r][c], 0, 0, 0);
                aR[r][c] = __builtin_amdgcn_mfma_f32_16x16x32_bf16(fl[r], wrh, aR[r][c], 0, 0, 0);
                aR[r][c] = __builtin_amdgcn_mfma_f32_16x16x32_bf16(fh[r], wrl, aR[r][c], 0, 0, 0);
            }
        }
    }

    // ---- epilogue: bias/relu/add, store, per-block BN column reduction ----
    // C/D layout: row = (l>>4)*4 + i, col = l&15 within each 16x16 tile
#pragma unroll
    for (int c = 0; c < 2; ++c) {
        int col = (ct0 + c) * 16 + lr;
        float bv = b[col], brv = br[col];
        float cs = 0.f, cq = 0.f;
#pragma unroll
        for (int r = 0; r < 2; ++r) {
#pragma unroll
            for (int i = 0; i < 4; ++i) {
                float o = fmaxf(aC[r][c][i] + bv, 0.f) + fmaxf(aR[r][c][i] + brv, 0.f);
                int grow = block_row + r * 16 + lh * 4 + i;
                y[(size_t)grow * 128 + col] = o;
                cs += o;
                cq += o * o;
            }
        }
        cs += __shfl_xor(cs, 16); cs += __shfl_xor(cs, 32);
        cq += __shfl_xor(cq, 16); cq += __shfl_xor(cq, 32);
        if (lh == 0) { redS[col] = cs; redQ[col] = cq; }
    }
    __syncthreads();
    if (tid < 128) {
        atomicAdd(&colsum[tid], redS[tid]);
        atomicAdd(&colsumsq[tid], redQ[tid]);
    }
}

// ---------------- BN stats + apply fused (stats recomputed per block, trivial) ----------------
__global__ void apply2_kernel(float4* __restrict__ y4,
                              const float* __restrict__ colsum, const float* __restrict__ colsumsq,
                              const float* __restrict__ gamma, const float* __restrict__ beta) {
    __shared__ float sc4[128], sh4[128];
    int t = threadIdx.x;
    if (t < 128) {
        const float inv_n = 1.0f / (float)NN;
        float mean = colsum[t] * inv_n;
        float var = colsumsq[t] * inv_n - mean * mean;
        float s = gamma[t] * rsqrtf(var + BN_EPS);
        sc4[t] = s;
        sh4[t] = beta[t] - mean * s;
    }
    __syncthreads();
    int i = blockIdx.x * 256 + t;
    if (i < NN * 32) {
        int c = (i & 31) * 4;
        float4 v = y4[i];
        v.x = v.x * sc4[c + 0] + sh4[c + 0];
        v.y = v.y * sc4[c + 1] + sh4[c + 1];
        v.z = v.z * sc4[c + 2] + sh4[c + 2];
        v.w = v.w * sc4[c + 3] + sh4[c + 3];
        y4[i] = v;
    }
}

extern "C" void kernel_launch(void* const* d_in, const int* in_sizes, int n_in,
                              void* d_out, int out_size, void* d_ws, size_t ws_size,
                              hipStream_t stream) {
    const float* feats = (const float*)d_in[0];
    const int* src = (const int*)d_in[1];
    const int* dst = (const int*)d_in[2];
    const float* W = (const float*)d_in[3];
    const float* b = (const float*)d_in[4];
    const float* Wr = (const float*)d_in[5];
    const float* br = (const float*)d_in[6];
    const float* gamma = (const float*)d_in[7];
    const float* beta = (const float*)d_in[8];
    float* y = (float*)d_out;

    // workspace carve
    char* ws = (char*)d_ws;
    ushort4* fb4 = (ushort4*)ws;                              // NN*32 ushort4 = 25.6 MB
    int* outdeg = (int*)(ws + (size_t)NN * 32 * 8);           // NN
    int* indeg = outdeg + NN;                                 // NN
    float* ns = (float*)(indeg + NN);                         // NN
    float* nd = ns + NN;                                      // NN
    int* row_ofs = (int*)(nd + NN);                           // NN+1
    int* cursor = row_ofs + NN + 1;                           // NN
    int* partial = cursor + NN;                               // NN
    int* blocksum = partial + NN;                             // 98
    int* blockofs = blocksum + 128;                           // (unused slot kept for layout)
    int* e_src = blockofs + 128;                              // EE
    float* colsum = (float*)(e_src + EE);                     // 128
    float* colsumsq = colsum + DD;                            // 128
    // wb: 256B-aligned, 2 gemms x 2 parts x 32 frags x 64 lanes x 8 bf16 = 128 KB
    unsigned long long wbofs = (unsigned long long)((char*)(colsumsq + DD) - ws);
    wbofs = (wbofs + 255ull) & ~255ull;
    unsigned short* wb = (unsigned short*)(ws + wbofs);

    hipMemsetAsync(outdeg, 0, 2 * (size_t)NN * sizeof(int), stream);
    hipMemsetAsync(colsum, 0, 2 * (size_t)DD * sizeof(float), stream);

    prepw_kernel<<<64, 64, 0, stream>>>(W, Wr, wb);
    deg4_kernel<<<(EE / 4 + 255) / 256, 256, 0, stream>>>((const int4*)src, (const int4*)dst,
                                                          outdeg, indeg);
    scan1_kernel<<<98, 1024, 0, stream>>>(indeg, partial, blocksum);
    scan23_kernel<<<(NN + 255) / 256, 256, 0, stream>>>(partial, blocksum, outdeg, indeg,
                                                        row_ofs, cursor, ns, nd);
    cvt_kernel<<<(NN * 32 + 255) / 256, 256, 0, stream>>>((const float4*)feats, ns, fb4);
    fill4_kernel<<<(EE / 4 + 255) / 256, 256, 0, stream>>>((const int4*)src, (const int4*)dst,
                                                           cursor, e_src);
    gg_kernel<<<NN / 32, 256, 0, stream>>>((const float4*)feats, fb4, nd, row_ofs, e_src,
                                           wb, b, br, y, colsum, colsumsq);
    apply2_kernel<<<(NN * 32 + 255) / 256, 256, 0, stream>>>((float4*)y, colsum, colsumsq,
                                                             gamma, beta);
}

// Round 2
// 502.386 us; speedup vs baseline: 1.2284x; 1.1211x over previous
//
#include <hip/hip_runtime.h>

#define NN 100000
#define DD 128
#define EE 1600000
#define BN_EPS 1e-5f

using bf16x8 = __attribute__((ext_vector_type(8))) short;
using f32x4  = __attribute__((ext_vector_type(4))) float;

__device__ __forceinline__ unsigned short bf16r(float f) {
    unsigned u = __float_as_uint(f);
    u += 0x7FFF + ((u >> 16) & 1);   // round-to-nearest-even
    return (unsigned short)(u >> 16);
}
__device__ __forceinline__ float bf2f(unsigned short h) {
    return __uint_as_float((unsigned)h << 16);
}

// ---------------- degree histogram + per-edge rank (int4 edge loads) ----------------
// rank[e] = position of edge e within its dst bucket (the atomicAdd return we used
// to discard) -> fill becomes atomic-free.
__global__ void deg4_kernel(const int4* __restrict__ src4, const int4* __restrict__ dst4,
                            int* __restrict__ outdeg, int* __restrict__ indeg,
                            int4* __restrict__ rank4) {
    int i = blockIdx.x * blockDim.x + threadIdx.x;
    if (i < EE / 4) {
        int4 s = src4[i];
        int4 d = dst4[i];
        atomicAdd(&outdeg[s.x], 1); atomicAdd(&outdeg[s.y], 1);
        atomicAdd(&outdeg[s.z], 1); atomicAdd(&outdeg[s.w], 1);
        int4 r;
        r.x = atomicAdd(&indeg[d.x], 1);
        r.y = atomicAdd(&indeg[d.y], 1);
        r.z = atomicAdd(&indeg[d.z], 1);
        r.w = atomicAdd(&indeg[d.w], 1);
        rank4[i] = r;
    }
}

// ---------------- scan phase 1: per-block inclusive scan of indeg ----------------
__global__ __launch_bounds__(1024) void scan1_kernel(const int* __restrict__ indeg,
                                                     int* __restrict__ partial,
                                                     int* __restrict__ blocksum) {
    __shared__ int s[1024];
    int t = threadIdx.x;
    int idx = blockIdx.x * 1024 + t;
    int v = (idx < NN) ? indeg[idx] : 0;
    s[t] = v;
    __syncthreads();
    for (int off = 1; off < 1024; off <<= 1) {
        int x = (t >= off) ? s[t - off] : 0;
        __syncthreads();
        s[t] += x;
        __syncthreads();
    }
    if (idx < NN) partial[idx] = s[t] - v;  // exclusive within block
    if (t == 1023) blocksum[blockIdx.x] = s[t];
}

// ---------------- scan phases 2+3 fused: every block re-scans the 98 block sums ----------------
__global__ void scan23_kernel(const int* __restrict__ partial, const int* __restrict__ blocksum,
                              const int* __restrict__ outdeg, const int* __restrict__ indeg,
                              int* __restrict__ row_ofs,
                              float* __restrict__ ns, float* __restrict__ nd) {
    __shared__ int s[128];
    int t = threadIdx.x;
    if (t < 128) s[t] = (t < 98) ? blocksum[t] : 0;
    __syncthreads();
    for (int off = 1; off < 128; off <<= 1) {
        int x = (t < 128 && t >= off) ? s[t - off] : 0;
        __syncthreads();
        if (t < 128) s[t] += x;
        __syncthreads();
    }
    int i = blockIdx.x * blockDim.x + t;
    if (i < NN) {
        int bk = i >> 10;
        int ro = partial[i] + s[bk] - blocksum[bk];  // + exclusive block offset
        row_ofs[i] = ro;
        ns[i] = rsqrtf(fmaxf((float)outdeg[i], 1.0f));
        nd[i] = rsqrtf(fmaxf((float)indeg[i], 1.0f));
        if (i == 0) row_ofs[NN] = EE;
    }
}

// ---------------- feats -> bf16 pre-scaled by ns ----------------
__global__ void cvt_kernel(const float4* __restrict__ feats4, const float* __restrict__ ns,
                           ushort4* __restrict__ fb4) {
    int i = blockIdx.x * blockDim.x + threadIdx.x;  // NN*32 = 3.2M
    if (i < NN * 32) {
        float s = ns[i >> 5];
        float4 v = feats4[i];
        ushort4 h;
        h.x = bf16r(v.x * s);
        h.y = bf16r(v.y * s);
        h.z = bf16r(v.z * s);
        h.w = bf16r(v.w * s);
        fb4[i] = h;
    }
}

// ---------------- CSR fill, atomic-free: slot = row_ofs[dst] + rank ----------------
__global__ void fill4_kernel(const int4* __restrict__ src4, const int4* __restrict__ dst4,
                             const int4* __restrict__ rank4, const int* __restrict__ row_ofs,
                             int* __restrict__ e_src) {
    int i = blockIdx.x * blockDim.x + threadIdx.x;
    if (i < EE / 4) {
        int4 s = src4[i];
        int4 d = dst4[i];
        int4 r = rank4[i];
        e_src[row_ofs[d.x] + r.x] = s.x;
        e_src[row_ofs[d.y] + r.y] = s.y;
        e_src[row_ofs[d.z] + r.z] = s.z;
        e_src[row_ofs[d.w] + r.w] = s.w;
    }
}

// ---------------- weight pre-pack into MFMA B-fragment order, bf16 hi/lo ----------------
// layout: wb[(g*2+p)*32 + ct*4 + ks][lane 0..63][i 0..7] bf16, fragment = 1KB contiguous
// B-frag for mfma_f32_16x16x32_bf16: lane l, elem i -> B[k = ks*32 + (l>>4)*8 + i][col = ct*16 + (l&15)]
__global__ void prepw_kernel(const float* __restrict__ W, const float* __restrict__ Wr,
                             unsigned short* __restrict__ wb) {
    int g = blockIdx.x >> 5;          // 0 = W, 1 = Wr
    int f = blockIdx.x & 31;          // ct*4 + ks
    int ct = f >> 2, ks = f & 3;
    int l = threadIdx.x;              // 0..63
    const float* G = g ? Wr : W;
    unsigned short* hi = wb + (((size_t)(g * 2 + 0) * 32 + f) * 64 + l) * 8;
    unsigned short* lo = wb + (((size_t)(g * 2 + 1) * 32 + f) * 64 + l) * 8;
    for (int i = 0; i < 8; ++i) {
        int k = ks * 32 + (l >> 4) * 8 + i;
        int col = ct * 16 + (l & 15);
        float w = G[k * 128 + col];
        unsigned uh = __float_as_uint(w) & 0xFFFF0000u;  // truncated hi part
        hi[i] = (unsigned short)(uh >> 16);
        lo[i] = bf16r(w - __uint_as_float(uh));          // residual -> lo
    }
}

// ---------------- fused gather + dual MFMA GEMM + bias/relu/add + BN colsum ----------------
// block = 256 threads (4 waves), 32 nodes/block, 3125 blocks.
// LDS exactly 32768B (red arrays alias AsH after a barrier) -> 5 blocks/CU;
// __launch_bounds__(256,5): 20 waves/CU for the latency-bound gather.
__global__ __launch_bounds__(256, 5) void gg_kernel(
    const float4* __restrict__ feats4, const ushort4* __restrict__ fb4,
    const float* __restrict__ nd,
    const int* __restrict__ row_ofs, const int* __restrict__ e_src,
    const unsigned short* __restrict__ wb,
    const float* __restrict__ b, const float* __restrict__ br,
    float* __restrict__ y, float* __restrict__ colsum, float* __restrict__ colsumsq) {
    __shared__ unsigned short AsH[32 * 128];
    __shared__ unsigned short AsL[32 * 128];
    __shared__ unsigned short FsH[32 * 128];
    __shared__ unsigned short FsL[32 * 128];

    const int tid = threadIdx.x;
    const int block_row = blockIdx.x * 32;

    // ---- stage residual feats rows as bf16 hi/lo (swizzled) ----
    for (int i = tid; i < 1024; i += 256) {
        int r = i >> 5;
        int c4 = i & 31;
        float4 f = feats4[(size_t)(block_row + r) * 32 + c4];
        unsigned u0 = __float_as_uint(f.x) & 0xFFFF0000u;
        unsigned u1 = __float_as_uint(f.y) & 0xFFFF0000u;
        unsigned u2 = __float_as_uint(f.z) & 0xFFFF0000u;
        unsigned u3 = __float_as_uint(f.w) & 0xFFFF0000u;
        ushort4 h, lo;
        h.x = (unsigned short)(u0 >> 16);
        h.y = (unsigned short)(u1 >> 16);
        h.z = (unsigned short)(u2 >> 16);
        h.w = (unsigned short)(u3 >> 16);
        lo.x = bf16r(f.x - __uint_as_float(u0));
        lo.y = bf16r(f.y - __uint_as_float(u1));
        lo.z = bf16r(f.z - __uint_as_float(u2));
        lo.w = bf16r(f.w - __uint_as_float(u3));
        int off = (r * 256 + ((c4 * 8) ^ ((r & 7) << 4))) >> 1;  // ushort index, 8B aligned
        *(ushort4*)(&FsH[off]) = h;
        *(ushort4*)(&FsL[off]) = lo;
    }

    // ---- gather-aggregate from bf16 pre-scaled table: each 32-lane group does 4 nodes ----
    {
        const int lane = tid & 31;
        const int grp = tid >> 5;
        for (int n = 0; n < 4; ++n) {
            int nl = grp * 4 + n;
            int node = block_row + nl;
            int beg = row_ofs[node];
            int end = row_ofs[node + 1];
            float4 acc0 = {0.f, 0.f, 0.f, 0.f};
            float4 acc1 = {0.f, 0.f, 0.f, 0.f};
            int e = beg;
            for (; e + 3 < end; e += 4) {
                int s0 = e_src[e], s1 = e_src[e + 1], s2 = e_src[e + 2], s3 = e_src[e + 3];
                ushort4 u0 = fb4[s0 * 32 + lane];
                ushort4 u1 = fb4[s1 * 32 + lane];
                ushort4 u2 = fb4[s2 * 32 + lane];
                ushort4 u3 = fb4[s3 * 32 + lane];
                acc0.x += bf2f(u0.x); acc0.y += bf2f(u0.y); acc0.z += bf2f(u0.z); acc0.w += bf2f(u0.w);
                acc1.x += bf2f(u1.x); acc1.y += bf2f(u1.y); acc1.z += bf2f(u1.z); acc1.w += bf2f(u1.w);
                acc0.x += bf2f(u2.x); acc0.y += bf2f(u2.y); acc0.z += bf2f(u2.z); acc0.w += bf2f(u2.w);
                acc1.x += bf2f(u3.x); acc1.y += bf2f(u3.y); acc1.z += bf2f(u3.z); acc1.w += bf2f(u3.w);
            }
            for (; e < end; ++e) {
                int s0 = e_src[e];
                ushort4 u0 = fb4[s0 * 32 + lane];
                acc0.x += bf2f(u0.x); acc0.y += bf2f(u0.y); acc0.z += bf2f(u0.z); acc0.w += bf2f(u0.w);
            }
            float snd = nd[node];
            float ax = (acc0.x + acc1.x) * snd;
            float ay = (acc0.y + acc1.y) * snd;
            float az = (acc0.z + acc1.z) * snd;
            float aw = (acc0.w + acc1.w) * snd;
            unsigned u0 = __float_as_uint(ax) & 0xFFFF0000u;
            unsigned u1 = __float_as_uint(ay) & 0xFFFF0000u;
            unsigned u2 = __float_as_uint(az) & 0xFFFF0000u;
            unsigned u3 = __float_as_uint(aw) & 0xFFFF0000u;
            ushort4 h, lo;
            h.x = (unsigned short)(u0 >> 16);
            h.y = (unsigned short)(u1 >> 16);
            h.z = (unsigned short)(u2 >> 16);
            h.w = (unsigned short)(u3 >> 16);
            lo.x = bf16r(ax - __uint_as_float(u0));
            lo.y = bf16r(ay - __uint_as_float(u1));
            lo.z = bf16r(az - __uint_as_float(u2));
            lo.w = bf16r(aw - __uint_as_float(u3));
            int off = (nl * 256 + ((lane * 8) ^ ((nl & 7) << 4))) >> 1;
            *(ushort4*)(&AsH[off]) = h;
            *(ushort4*)(&AsL[off]) = lo;
        }
    }
    __syncthreads();

    // ---- MFMA phase: wave w covers all 32 rows x cols [w*32, w*32+31] ----
    const int w = tid >> 6;
    const int l = tid & 63;
    const int lr = l & 15;
    const int lh = l >> 4;
    const int ct0 = w * 2;
    const bf16x8* WB = (const bf16x8*)wb;

    const f32x4 fzero = {0.f, 0.f, 0.f, 0.f};
    f32x4 aC[2][2], aR[2][2];  // [row-frag][col-tile]
#pragma unroll
    for (int r = 0; r < 2; ++r)
#pragma unroll
        for (int c = 0; c < 2; ++c) { aC[r][c] = fzero; aR[r][c] = fzero; }

#pragma unroll 1
    for (int ks = 0; ks < 4; ++ks) {
        bf16x8 ah[2], al[2], fh[2], fl[2];
#pragma unroll
        for (int r = 0; r < 2; ++r) {
            int row = r * 16 + lr;
            int off = (row * 256 + ((ks * 64 + lh * 16) ^ ((row & 7) << 4))) >> 1;
            ah[r] = *(const bf16x8*)(&AsH[off]);
            al[r] = *(const bf16x8*)(&AsL[off]);
            fh[r] = *(const bf16x8*)(&FsH[off]);
            fl[r] = *(const bf16x8*)(&FsL[off]);
        }
#pragma unroll
        for (int c = 0; c < 2; ++c) {
            int fr = (ct0 + c) * 4 + ks;
            bf16x8 wh  = WB[(0 * 32 + fr) * 64 + l];
            bf16x8 wl  = WB[(1 * 32 + fr) * 64 + l];
            bf16x8 wrh = WB[(2 * 32 + fr) * 64 + l];
            bf16x8 wrl = WB[(3 * 32 + fr) * 64 + l];
#pragma unroll
            for (int r = 0; r < 2; ++r) {
                aC[r][c] = __builtin_amdgcn_mfma_f32_16x16x32_bf16(ah[r], wh, aC[r][c], 0, 0, 0);
                aC[r][c] = __builtin_amdgcn_mfma_f32_16x16x32_bf16(al[r], wh, aC[r][c], 0, 0, 0);
                aC[r][c] = __builtin_amdgcn_mfma_f32_16x16x32_bf16(ah[r], wl, aC[r][c], 0, 0, 0);
                aR[r][c] = __builtin_amdgcn_mfma_f32_16x16x32_bf16(fh[r], wrh, aR[r][c], 0, 0, 0);
                aR[r][c] = __builtin_amdgcn_mfma_f32_16x16x32_bf16(fl[r], wrh, aR[r][c], 0, 0, 0);
                aR[r][c] = __builtin_amdgcn_mfma_f32_16x16x32_bf16(fh[r], wrl, aR[r][c], 0, 0, 0);
            }
        }
    }

    // all LDS tile reads are done -> barrier, then alias reduction scratch onto AsH
    __syncthreads();
    float* redS = (float*)AsH;        // 128 floats
    float* redQ = ((float*)AsH) + 128;

    // ---- epilogue: bias/relu/add, store, per-block BN column reduction ----
    // C/D layout: row = (l>>4)*4 + i, col = l&15 within each 16x16 tile
#pragma unroll
    for (int c = 0; c < 2; ++c) {
        int col = (ct0 + c) * 16 + lr;
        float bv = b[col], brv = br[col];
        float cs = 0.f, cq = 0.f;
#pragma unroll
        for (int r = 0; r < 2; ++r) {
#pragma unroll
            for (int i = 0; i < 4; ++i) {
                float o = fmaxf(aC[r][c][i] + bv, 0.f) + fmaxf(aR[r][c][i] + brv, 0.f);
                int grow = block_row + r * 16 + lh * 4 + i;
                y[(size_t)grow * 128 + col] = o;
                cs += o;
                cq += o * o;
            }
        }
        cs += __shfl_xor(cs, 16); cs += __shfl_xor(cs, 32);
        cq += __shfl_xor(cq, 16); cq += __shfl_xor(cq, 32);
        if (lh == 0) { redS[col] = cs; redQ[col] = cq; }
    }
    __syncthreads();
    if (tid < 128) {
        atomicAdd(&colsum[tid], redS[tid]);
        atomicAdd(&colsumsq[tid], redQ[tid]);
    }
}

// ---------------- BN stats + apply fused (stats recomputed per block, trivial) ----------------
__global__ void apply2_kernel(float4* __restrict__ y4,
                              const float* __restrict__ colsum, const float* __restrict__ colsumsq,
                              const float* __restrict__ gamma, const float* __restrict__ beta) {
    __shared__ float sc4[128], sh4[128];
    int t = threadIdx.x;
    if (t < 128) {
        const float inv_n = 1.0f / (float)NN;
        float mean = colsum[t] * inv_n;
        float var = colsumsq[t] * inv_n - mean * mean;
        float s = gamma[t] * rsqrtf(var + BN_EPS);
        sc4[t] = s;
        sh4[t] = beta[t] - mean * s;
    }
    __syncthreads();
    int i = blockIdx.x * 256 + t;
    if (i < NN * 32) {
        int c = (i & 31) * 4;
        float4 v = y4[i];
        v.x = v.x * sc4[c + 0] + sh4[c + 0];
        v.y = v.y * sc4[c + 1] + sh4[c + 1];
        v.z = v.z * sc4[c + 2] + sh4[c + 2];
        v.w = v.w * sc4[c + 3] + sh4[c + 3];
        y4[i] = v;
    }
}

extern "C" void kernel_launch(void* const* d_in, const int* in_sizes, int n_in,
                              void* d_out, int out_size, void* d_ws, size_t ws_size,
                              hipStream_t stream) {
    const float* feats = (const float*)d_in[0];
    const int* src = (const int*)d_in[1];
    const int* dst = (const int*)d_in[2];
    const float* W = (const float*)d_in[3];
    const float* b = (const float*)d_in[4];
    const float* Wr = (const float*)d_in[5];
    const float* br = (const float*)d_in[6];
    const float* gamma = (const float*)d_in[7];
    const float* beta = (const float*)d_in[8];
    float* y = (float*)d_out;

    // workspace carve
    char* ws = (char*)d_ws;
    ushort4* fb4 = (ushort4*)ws;                              // NN*32 ushort4 = 25.6 MB
    int* outdeg = (int*)(ws + (size_t)NN * 32 * 8);           // NN
    int* indeg = outdeg + NN;                                 // NN
    float* ns = (float*)(indeg + NN);                         // NN
    float* nd = ns + NN;                                      // NN
    int* row_ofs = (int*)(nd + NN);                           // NN+1
    int* partial = row_ofs + NN + 1;                          // NN
    int* blocksum = partial + NN;                             // 98 (pad 128)
    int* e_src = blocksum + 128;                              // EE
    float* colsum = (float*)(e_src + EE);                     // 128
    float* colsumsq = colsum + DD;                            // 128
    // wb: 256B-aligned, 2 gemms x 2 parts x 32 frags x 64 lanes x 8 bf16 = 128 KB
    unsigned long long wbofs = (unsigned long long)((char*)(colsumsq + DD) - ws);
    wbofs = (wbofs + 255ull) & ~255ull;
    unsigned short* wb = (unsigned short*)(ws + wbofs);
    // rank: 16B-aligned, EE ints = 6.4 MB
    unsigned long long rkofs = wbofs + (unsigned long long)4 * 32 * 64 * 8 * 2;
    rkofs = (rkofs + 255ull) & ~255ull;
    int4* rank4 = (int4*)(ws + rkofs);

    hipMemsetAsync(outdeg, 0, 2 * (size_t)NN * sizeof(int), stream);
    hipMemsetAsync(colsum, 0, 2 * (size_t)DD * sizeof(float), stream);

    prepw_kernel<<<64, 64, 0, stream>>>(W, Wr, wb);
    deg4_kernel<<<(EE / 4 + 255) / 256, 256, 0, stream>>>((const int4*)src, (const int4*)dst,
                                                          outdeg, indeg, rank4);
    scan1_kernel<<<98, 1024, 0, stream>>>(indeg, partial, blocksum);
    scan23_kernel<<<(NN + 255) / 256, 256, 0, stream>>>(partial, blocksum, outdeg, indeg,
                                                        row_ofs, ns, nd);
    cvt_kernel<<<(NN * 32 + 255) / 256, 256, 0, stream>>>((const float4*)feats, ns, fb4);
    fill4_kernel<<<(EE / 4 + 255) / 256, 256, 0, stream>>>((const int4*)src, (const int4*)dst,
                                                           rank4, row_ofs, e_src);
    gg_kernel<<<NN / 32, 256, 0, stream>>>((const float4*)feats, fb4, nd, row_ofs, e_src,
                                           wb, b, br, y, colsum, colsumsq);
    apply2_kernel<<<(NN * 32 + 255) / 256, 256, 0, stream>>>((float4*)y, colsum, colsumsq,
                                                             gamma, beta);
}